// Round 2
// baseline (191.167 us; speedup 1.0000x reference)
//
#include <hip/hip_runtime.h>
#include <hip/hip_bf16.h>

// Problem constants
#define BB 8
#define CIN 128
#define HH 48
#define WW 48
#define HW 2304          // 48*48
#define KK 9
#define COUT 256
#define KC 1152          // K*CIN
#define MM 18432         // B*HW

typedef short bf16x8_t __attribute__((ext_vector_type(8)));
typedef float f32x16_t __attribute__((ext_vector_type(16)));

// ---------------------------------------------------------------------------
// Kernel 1: per-position MLP -> means/sigmas/fl  (batch independent, fp64)
// ---------------------------------------------------------------------------
__global__ __launch_bounds__(64) void params_kernel(
    const float* __restrict__ W1, const float* __restrict__ b1,
    const float* __restrict__ W2, const float* __restrict__ b2,
    float* __restrict__ means, float* __restrict__ sigmas, int* __restrict__ fls)
{
    int p = blockIdx.x;            // position 0..2303
    int iy = p / WW, ix = p % WW;
    float ryf = (float)iy / 47.0f; // coords computed in fp32 like reference
    float rxf = (float)ix / 47.0f;
    double ry = (double)ryf, rx = (double)rxf;

    __shared__ double hid[512];
    __shared__ double par[27];
    int t = threadIdx.x;

    for (int j = t; j < 512; j += 64) {
        double v = ry * (double)W1[j*2+0] + rx * (double)W1[j*2+1] + (double)b1[j];
        hid[j] = v > 0.0 ? v : 0.0;
    }
    __syncthreads();
    if (t < 27) {
        const float* w = W2 + t * 512;
        double acc = 0.0;
        for (int j = 0; j < 512; j++) acc += (double)w[j] * hid[j];
        par[t] = acc + (double)b2[t];
    }
    __syncthreads();
    if (t < KK) {
        double pixy = ry * 47.0;
        double pixx = rx * 47.0;
        double scy = pixy / 47.0 * 0.9999 + 5e-05;
        double scx = pixx / 47.0 * 0.9999 + 5e-05;
        double midy = log(scy / (1.0 - scy));
        double midx = log(scx / (1.0 - scx));
        double zy = midy + 0.1 * par[2*t+0];
        double zx = midx + 0.1 * par[2*t+1];
        double my = 47.0 / (1.0 + exp(-zy));
        double mx = 47.0 / (1.0 + exp(-zx));
        double sr = par[18 + t] + 2.0;
        double sp = (sr > 0.0 ? sr : 0.0) + log1p(exp(-fabs(sr)));
        double sg = (sp + 0.05) * 48.0 * 0.05;

        means[(p*KK + t)*2 + 0] = (float)my;
        means[(p*KK + t)*2 + 1] = (float)mx;
        sigmas[p*KK + t] = (float)sg;
        fls[(p*KK + t)*2 + 0] = (int)floor(my);
        fls[(p*KK + t)*2 + 1] = (int)floor(mx);
    }
}

// ---------------------------------------------------------------------------
// Kernel 2: transpose x (b,c,h,w) fp32 -> xT (b,hw,c) bf16
// ---------------------------------------------------------------------------
__global__ __launch_bounds__(256) void transpose_kernel(
    const float* __restrict__ x, __hip_bfloat16* __restrict__ xT)
{
    __shared__ float tile[64][65];
    int b = blockIdx.z;
    int c0 = blockIdx.y * 64;
    int ij0 = blockIdx.x * 64;
    int t = threadIdx.x;
    int ijl = t & 63, cl = t >> 6;     // cl 0..3
    #pragma unroll
    for (int i = 0; i < 16; i++) {
        int cc = i*4 + cl;
        tile[cc][ijl] = x[(size_t)(b*CIN + c0 + cc) * HW + ij0 + ijl];
    }
    __syncthreads();
    int cl2 = t & 63, ijl2 = t >> 6;
    #pragma unroll
    for (int i = 0; i < 16; i++) {
        int ij = i*4 + ijl2;
        xT[(size_t)(b*HW + ij0 + ij) * CIN + c0 + cl2] = __float2bfloat16(tile[cl2][ij]);
    }
}

// ---------------------------------------------------------------------------
// Kernel 3: cast Wu fp32 -> bf16
// ---------------------------------------------------------------------------
__global__ __launch_bounds__(256) void cast_kernel(
    const float* __restrict__ src, __hip_bfloat16* __restrict__ dst, int n)
{
    int i = blockIdx.x * blockDim.x + threadIdx.x;
    if (i < n) dst[i] = __float2bfloat16(src[i]);
}

// ---------------------------------------------------------------------------
// Kernel 4: gather taps, weights (dup-kill + normalize), weighted feature sum
// one block (128 threads) per (b, ij); feats out bf16 [M, 1152]
// ---------------------------------------------------------------------------
__global__ __launch_bounds__(128) void gather_kernel(
    const float* __restrict__ means, const float* __restrict__ sigmas,
    const int* __restrict__ fls, const int* __restrict__ gints,
    const int* __restrict__ roff, const __hip_bfloat16* __restrict__ xT,
    __hip_bfloat16* __restrict__ feats)
{
    int bij = blockIdx.x;
    int b = bij / HW;
    int ij = bij % HW;
    int t = threadIdx.x;

    __shared__ int s_lin[72];
    __shared__ float s_w[72];

    if (t < 72) {
        int k = t >> 3, v = t & 7;
        int fy = fls[(ij*KK + k)*2 + 0];
        int fx = fls[(ij*KK + k)*2 + 1];
        int iy, ix;
        if (v < 4) {
            iy = fy + (v >> 1); ix = fx + (v & 1);
        } else if (v < 6) {
            int base = ((bij*KK + k)*2 + (v - 4)) * 2;
            iy = gints[base]; ix = gints[base + 1];
        } else {
            int base = ((bij*KK + k)*2 + (v - 6)) * 2;
            iy = fy + roff[base] - 6; ix = fx + roff[base + 1] - 6;
        }
        iy = ((iy % HH) + HH) % HH;
        ix = ((ix % WW) + WW) % WW;
        s_lin[t] = iy * WW + ix;
        float my = means[(ij*KK + k)*2 + 0];
        float mx = means[(ij*KK + k)*2 + 1];
        float sg = sigmas[ij*KK + k];
        float dy = ((float)iy - my) / sg;
        float dx = ((float)ix - mx) / sg;
        s_w[t] = expf(-0.5f * (dy*dy + dx*dx));
    }
    __syncthreads();
    if (t < KK) {
        int base = t * 8;
        int lins[8]; float ws[8];
        #pragma unroll
        for (int v = 0; v < 8; v++) { lins[v] = s_lin[base+v]; ws[v] = s_w[base+v]; }
        #pragma unroll
        for (int v = 1; v < 8; v++) {
            bool dup = false;
            #pragma unroll
            for (int u = 0; u < 8; u++) if (u < v) dup = dup || (lins[u] == lins[v]);
            if (dup) ws[v] = 0.0f;
        }
        float sum = 0.0f;
        #pragma unroll
        for (int v = 0; v < 8; v++) sum += ws[v];
        float inv = 1.0f / sum;
        #pragma unroll
        for (int v = 0; v < 8; v++) s_w[base+v] = ws[v] * inv;
    }
    __syncthreads();

    const __hip_bfloat16* xb = xT + (size_t)b * (HW * CIN);
    __hip_bfloat16* fo = feats + (size_t)bij * KC;
    #pragma unroll
    for (int k = 0; k < KK; k++) {
        float a = 0.0f;
        #pragma unroll
        for (int v = 0; v < 8; v++) {
            a += s_w[k*8+v] * __bfloat162float(xb[(size_t)s_lin[k*8+v] * CIN + t]);
        }
        fo[k*CIN + t] = __float2bfloat16(a);
    }
}

// ---------------------------------------------------------------------------
// Kernel 5: GEMM  out[m,n] = feats[m,:] . Wu[n,:] + bu[n]
// no-LDS wave tile: 64m x 64n per wave (MFMA 32x32x16 bf16, 2x2 frags)
// K-loop: 72 iterations x 16 = 1152 = KC   (round-1 fix: was 36 -> half K)
// out layout: (b, n, ij) fp32
// ---------------------------------------------------------------------------
__global__ __launch_bounds__(64) void gemm_kernel(
    const __hip_bfloat16* __restrict__ A,   // feats [M, KC]
    const __hip_bfloat16* __restrict__ Bw,  // Wu bf16 [COUT, KC]
    const float* __restrict__ bu,
    float* __restrict__ out)
{
    int wid = blockIdx.x;
    int mt = wid >> 2, nt = wid & 3;
    int m0 = mt * 64, n0 = nt * 64;
    int lane = threadIdx.x;
    int r = lane & 31, q = lane >> 5;

    const bf16x8_t* A0p = (const bf16x8_t*)(A + (size_t)(m0 + r) * KC) + q;
    const bf16x8_t* A1p = A0p + 32 * (KC / 8);
    const bf16x8_t* B0p = (const bf16x8_t*)(Bw + (size_t)(n0 + r) * KC) + q;
    const bf16x8_t* B1p = B0p + 32 * (KC / 8);

    f32x16_t acc[2][2] = {};
    bf16x8_t a0c = A0p[0], a1c = A1p[0], b0c = B0p[0], b1c = B1p[0];
    bf16x8_t a0n = A0p[2], a1n = A1p[2], b0n = B0p[2], b1n = B1p[2];

    #pragma unroll
    for (int i = 0; i < 72; i++) {       // K = 72 * 16 = 1152
        acc[0][0] = __builtin_amdgcn_mfma_f32_32x32x16_bf16(a0c, b0c, acc[0][0], 0, 0, 0);
        acc[0][1] = __builtin_amdgcn_mfma_f32_32x32x16_bf16(a0c, b1c, acc[0][1], 0, 0, 0);
        acc[1][0] = __builtin_amdgcn_mfma_f32_32x32x16_bf16(a1c, b0c, acc[1][0], 0, 0, 0);
        acc[1][1] = __builtin_amdgcn_mfma_f32_32x32x16_bf16(a1c, b1c, acc[1][1], 0, 0, 0);
        a0c = a0n; a1c = a1n; b0c = b0n; b1c = b1n;
        if (i + 2 < 72) {
            int idx = 2*i + 4;
            a0n = A0p[idx]; a1n = A1p[idx]; b0n = B0p[idx]; b1n = B1p[idx];
        }
    }

    int bb = m0 / HW;
    int ij0 = m0 % HW;
    float* outb = out + (size_t)bb * COUT * HW;
    #pragma unroll
    for (int ni = 0; ni < 2; ni++) {
        int n = n0 + ni*32 + r;
        float bv = bu[n];
        float* oc = outb + (size_t)n * HW + ij0;
        #pragma unroll
        for (int mi = 0; mi < 2; mi++) {
            #pragma unroll
            for (int reg = 0; reg < 16; reg++) {
                int moff = mi*32 + (reg & 3) + 8*(reg >> 2) + 4*q;
                oc[moff] = acc[mi][ni][reg] + bv;
            }
        }
    }
}

// ---------------------------------------------------------------------------
extern "C" void kernel_launch(void* const* d_in, const int* in_sizes, int n_in,
                              void* d_out, int out_size, void* d_ws, size_t ws_size,
                              hipStream_t stream)
{
    const float* x   = (const float*)d_in[0];
    const float* W1  = (const float*)d_in[1];
    const float* b1  = (const float*)d_in[2];
    const float* W2  = (const float*)d_in[3];
    const float* b2  = (const float*)d_in[4];
    const float* Wu  = (const float*)d_in[5];
    const float* bu  = (const float*)d_in[6];
    const int* gints = (const int*)d_in[7];
    const int* roff  = (const int*)d_in[8];
    float* out = (float*)d_out;

    char* ws = (char*)d_ws;
    float* ws_means  = (float*)(ws + 0);                    // 2304*18 fp32
    float* ws_sigma  = (float*)(ws + 165888);               // 2304*9  fp32
    int*   ws_fl     = (int*  )(ws + 248832);               // 2304*18 int
    __hip_bfloat16* ws_xT    = (__hip_bfloat16*)(ws + 414720);   // 8*2304*128 bf16
    __hip_bfloat16* ws_wu    = (__hip_bfloat16*)(ws + 5133312);  // 256*1152 bf16
    __hip_bfloat16* ws_feats = (__hip_bfloat16*)(ws + 5723136);  // 18432*1152 bf16

    params_kernel<<<HW, 64, 0, stream>>>(W1, b1, W2, b2, ws_means, ws_sigma, ws_fl);
    transpose_kernel<<<dim3(HW/64, CIN/64, BB), 256, 0, stream>>>(x, ws_xT);
    cast_kernel<<<(COUT*KC + 255)/256, 256, 0, stream>>>(Wu, ws_wu, COUT*KC);
    gather_kernel<<<MM, 128, 0, stream>>>(ws_means, ws_sigma, ws_fl, gints, roff,
                                          ws_xT, ws_feats);
    gemm_kernel<<<(MM/64) * (COUT/64), 64, 0, stream>>>(ws_feats, ws_wu, bu, out);
}

// Round 3
// 154.706 us; speedup vs baseline: 1.2357x; 1.2357x over previous
//
#include <hip/hip_runtime.h>
#include <hip/hip_bf16.h>

// Problem constants
#define BB 8
#define CIN 128
#define HH 48
#define WW 48
#define HW 2304          // 48*48
#define KK 9
#define COUT 256
#define KC 1152          // K*CIN
#define MM 18432         // B*HW
#define MT 32            // M-tile rows per block (fused kernel)
#define SFP 136          // feats LDS row stride in elements (16B-aligned, ~4-way bank)

typedef short bf16x8_t __attribute__((ext_vector_type(8)));
typedef float f32x16_t __attribute__((ext_vector_type(16)));
typedef float f32x4_t  __attribute__((ext_vector_type(4)));

static __device__ __forceinline__ float b2f(short u) {
    union { unsigned int i; float f; } c;
    c.i = ((unsigned int)(unsigned short)u) << 16;
    return c.f;
}

// ---------------------------------------------------------------------------
// Kernel 1: per-position MLP -> means/sigmas/fl  (batch independent, fp64)
// ---------------------------------------------------------------------------
__global__ __launch_bounds__(64) void params_kernel(
    const float* __restrict__ W1, const float* __restrict__ b1,
    const float* __restrict__ W2, const float* __restrict__ b2,
    float* __restrict__ means, float* __restrict__ sigmas, int* __restrict__ fls)
{
    int p = blockIdx.x;            // position 0..2303
    int iy = p / WW, ix = p % WW;
    float ryf = (float)iy / 47.0f; // coords computed in fp32 like reference
    float rxf = (float)ix / 47.0f;
    double ry = (double)ryf, rx = (double)rxf;

    __shared__ double hid[512];
    __shared__ double par[27];
    int t = threadIdx.x;

    for (int j = t; j < 512; j += 64) {
        double v = ry * (double)W1[j*2+0] + rx * (double)W1[j*2+1] + (double)b1[j];
        hid[j] = v > 0.0 ? v : 0.0;
    }
    __syncthreads();
    if (t < 27) {
        const float* w = W2 + t * 512;
        double acc = 0.0;
        for (int j = 0; j < 512; j++) acc += (double)w[j] * hid[j];
        par[t] = acc + (double)b2[t];
    }
    __syncthreads();
    if (t < KK) {
        double pixy = ry * 47.0;
        double pixx = rx * 47.0;
        double scy = pixy / 47.0 * 0.9999 + 5e-05;
        double scx = pixx / 47.0 * 0.9999 + 5e-05;
        double midy = log(scy / (1.0 - scy));
        double midx = log(scx / (1.0 - scx));
        double zy = midy + 0.1 * par[2*t+0];
        double zx = midx + 0.1 * par[2*t+1];
        double my = 47.0 / (1.0 + exp(-zy));
        double mx = 47.0 / (1.0 + exp(-zx));
        double sr = par[18 + t] + 2.0;
        double sp = (sr > 0.0 ? sr : 0.0) + log1p(exp(-fabs(sr)));
        double sg = (sp + 0.05) * 48.0 * 0.05;

        means[(p*KK + t)*2 + 0] = (float)my;
        means[(p*KK + t)*2 + 1] = (float)mx;
        sigmas[p*KK + t] = (float)sg;
        fls[(p*KK + t)*2 + 0] = (int)floor(my);
        fls[(p*KK + t)*2 + 1] = (int)floor(mx);
    }
}

// ---------------------------------------------------------------------------
// Kernel 2: transpose x (b,c,h,w) fp32 -> xT (b,hw,c) bf16
// ---------------------------------------------------------------------------
__global__ __launch_bounds__(256) void transpose_kernel(
    const float* __restrict__ x, __hip_bfloat16* __restrict__ xT)
{
    __shared__ float tile[64][65];
    int b = blockIdx.z;
    int c0 = blockIdx.y * 64;
    int ij0 = blockIdx.x * 64;
    int t = threadIdx.x;
    int ijl = t & 63, cl = t >> 6;     // cl 0..3
    #pragma unroll
    for (int i = 0; i < 16; i++) {
        int cc = i*4 + cl;
        tile[cc][ijl] = x[(size_t)(b*CIN + c0 + cc) * HW + ij0 + ijl];
    }
    __syncthreads();
    int cl2 = t & 63, ijl2 = t >> 6;
    #pragma unroll
    for (int i = 0; i < 16; i++) {
        int ij = i*4 + ijl2;
        xT[(size_t)(b*HW + ij0 + ij) * CIN + c0 + cl2] = __float2bfloat16(tile[cl2][ij]);
    }
}

// ---------------------------------------------------------------------------
// Kernel 3: pack Wu fp32 -> bf16 fragments
// Bp[((g*72 + s)*64 + lane)] = bf16x8 frag: Wu[g*32 + (lane&31)][s*16 + (lane>>5)*8 + j]
// g = n-group of 32 (8 groups), s = global kstep of 16 (72 steps)
// ---------------------------------------------------------------------------
__global__ __launch_bounds__(256) void pack_wu(
    const float* __restrict__ Wu, bf16x8_t* __restrict__ Bp)
{
    int idx = blockIdx.x * 256 + threadIdx.x;     // 0 .. 8*72*64-1 = 36863
    int lane = idx & 63;
    int rest = idx >> 6;
    int s = rest % 72, g = rest / 72;
    int r = lane & 31, qq = lane >> 5;
    const float* src = Wu + (size_t)(g*32 + r) * KC + s*16 + qq*8;
    union { bf16x8_t v; __hip_bfloat16 h[8]; } o;
    #pragma unroll
    for (int j = 0; j < 8; j++) o.h[j] = __float2bfloat16(src[j]);
    Bp[idx] = o.v;
}

// ---------------------------------------------------------------------------
// Kernel 4: FUSED gather + GEMM.
// Block: 256 threads (4 waves). M-tile = 32 rows (bij), full N = 256.
// Per k-chunk (9): gather 32x128 feats chunk into LDS (double-buffered),
// MFMA 32x32x16_bf16 against Wu fragments prefetched from packed Bp.
// out layout (b, cout, hw) fp32.
// ---------------------------------------------------------------------------
__global__ __launch_bounds__(256) void fused_kernel(
    const float* __restrict__ means, const float* __restrict__ sigmas,
    const int* __restrict__ fls, const int* __restrict__ gints,
    const int* __restrict__ roff, const short* __restrict__ xT,
    const bf16x8_t* __restrict__ Bp, const float* __restrict__ bu,
    float* __restrict__ out)
{
    __shared__ int   s_lin[KK*MT*8];
    __shared__ float s_w[KK*MT*8];
    __shared__ __align__(16) short s_feat[2][MT*SFP];

    int t = threadIdx.x;
    int m0 = blockIdx.x * MT;
    int b  = m0 / HW;
    int ij0 = m0 % HW;

    // ---- setup phase: taps, dup-kill, normalized weights for all (row, k)
    for (int p = t; p < KK*MT; p += 256) {
        int k = p >> 5, row = p & 31;
        int ij = ij0 + row;
        int bij = m0 + row;
        int fy = fls[(ij*KK + k)*2 + 0];
        int fx = fls[(ij*KK + k)*2 + 1];
        float my = means[(ij*KK + k)*2 + 0];
        float mx = means[(ij*KK + k)*2 + 1];
        float sg = sigmas[ij*KK + k];
        int lins[8]; float ws[8];
        #pragma unroll
        for (int v = 0; v < 8; v++) {
            int iy, ix;
            if (v < 4) {
                iy = fy + (v >> 1); ix = fx + (v & 1);
            } else if (v < 6) {
                int base = ((bij*KK + k)*2 + (v - 4)) * 2;
                iy = gints[base]; ix = gints[base + 1];
            } else {
                int base = ((bij*KK + k)*2 + (v - 6)) * 2;
                iy = fy + roff[base] - 6; ix = fx + roff[base + 1] - 6;
            }
            iy = ((iy % HH) + HH) % HH;
            ix = ((ix % WW) + WW) % WW;
            lins[v] = iy * WW + ix;
            float dy = ((float)iy - my) / sg;
            float dx = ((float)ix - mx) / sg;
            ws[v] = expf(-0.5f * (dy*dy + dx*dx));
        }
        #pragma unroll
        for (int v = 1; v < 8; v++) {
            bool dup = false;
            #pragma unroll
            for (int u = 0; u < 8; u++) if (u < v) dup = dup || (lins[u] == lins[v]);
            if (dup) ws[v] = 0.0f;
        }
        float sum = 0.0f;
        #pragma unroll
        for (int v = 0; v < 8; v++) sum += ws[v];
        float inv = 1.0f / sum;
        #pragma unroll
        for (int v = 0; v < 8; v++) { s_lin[p*8+v] = lins[v]; s_w[p*8+v] = ws[v] * inv; }
    }
    __syncthreads();

    const short* xb = xT + (size_t)b * (HW * CIN);
    int lane = t & 63, wave = t >> 6;
    int r = lane & 31, q = lane >> 5;
    int grow = t >> 3, gc0 = (t & 7) << 4;   // gather: row, channel base (16 ch)

    f32x16_t acc0 = {}, acc1 = {};

    for (int k = 0; k < KK; k++) {
        // ---- prefetch B fragments for this chunk (consumed after barrier;
        //      gather phase hides the L2 latency)
        bf16x8_t Bf0[8], Bf1[8];
        {
            int base = ((wave*2)*72 + k*8)*64 + lane;
            #pragma unroll
            for (int si = 0; si < 8; si++) {
                Bf0[si] = Bp[base + si*64];
                Bf1[si] = Bp[base + 72*64 + si*64];
            }
        }
        // ---- gather chunk k into s_feat[k&1]
        {
            const int*   lp = s_lin + (k*MT + grow)*8;
            const float* wp = s_w   + (k*MT + grow)*8;
            float a0[8], a1[8];
            #pragma unroll
            for (int j = 0; j < 8; j++) { a0[j] = 0.0f; a1[j] = 0.0f; }
            #pragma unroll
            for (int v = 0; v < 8; v++) {
                int lin = lp[v];
                float w = wp[v];
                const bf16x8_t* sp = (const bf16x8_t*)(xb + (size_t)lin * CIN + gc0);
                bf16x8_t d0 = sp[0], d1 = sp[1];
                #pragma unroll
                for (int j = 0; j < 8; j++) {
                    a0[j] += w * b2f(d0[j]);
                    a1[j] += w * b2f(d1[j]);
                }
            }
            union { bf16x8_t v8; __hip_bfloat16 h[8]; } o0, o1;
            #pragma unroll
            for (int j = 0; j < 8; j++) {
                o0.h[j] = __float2bfloat16(a0[j]);
                o1.h[j] = __float2bfloat16(a1[j]);
            }
            bf16x8_t* fd = (bf16x8_t*)(&s_feat[k & 1][grow*SFP + gc0]);
            fd[0] = o0.v8;
            fd[1] = o1.v8;
        }
        __syncthreads();
        // ---- MFMA over this chunk (A from LDS, B from regs)
        const short* fb = s_feat[k & 1];
        #pragma unroll
        for (int si = 0; si < 8; si++) {
            bf16x8_t a = *(const bf16x8_t*)(fb + r*SFP + si*16 + q*8);
            acc0 = __builtin_amdgcn_mfma_f32_32x32x16_bf16(a, Bf0[si], acc0, 0, 0, 0);
            acc1 = __builtin_amdgcn_mfma_f32_32x32x16_bf16(a, Bf1[si], acc1, 0, 0, 0);
        }
        // one barrier per chunk is sufficient: buf (k+2)&1 == k&1 is only
        // rewritten after sync(k+1), by which time all waves finished MFMA(k)
    }

    // ---- epilogue: C row = (reg&3)+8*(reg>>2)+4*q, col = r (n)
    #pragma unroll
    for (int h = 0; h < 2; h++) {
        int n = wave*64 + h*32 + r;
        float bv = bu[n];
        float* oc = out + ((size_t)b * COUT + n) * HW + ij0;
        const f32x16_t a = h ? acc1 : acc0;
        #pragma unroll
        for (int g4 = 0; g4 < 4; g4++) {
            f32x4_t vv;
            vv[0] = a[g4*4+0] + bv;
            vv[1] = a[g4*4+1] + bv;
            vv[2] = a[g4*4+2] + bv;
            vv[3] = a[g4*4+3] + bv;
            *(f32x4_t*)(oc + g4*8 + q*4) = vv;
        }
    }
}

// ---------------------------------------------------------------------------
extern "C" void kernel_launch(void* const* d_in, const int* in_sizes, int n_in,
                              void* d_out, int out_size, void* d_ws, size_t ws_size,
                              hipStream_t stream)
{
    const float* x   = (const float*)d_in[0];
    const float* W1  = (const float*)d_in[1];
    const float* b1  = (const float*)d_in[2];
    const float* W2  = (const float*)d_in[3];
    const float* b2  = (const float*)d_in[4];
    const float* Wu  = (const float*)d_in[5];
    const float* bu  = (const float*)d_in[6];
    const int* gints = (const int*)d_in[7];
    const int* roff  = (const int*)d_in[8];
    float* out = (float*)d_out;

    char* ws = (char*)d_ws;
    float* ws_means  = (float*)(ws + 0);                    // 2304*18 fp32
    float* ws_sigma  = (float*)(ws + 165888);               // 2304*9  fp32
    int*   ws_fl     = (int*  )(ws + 248832);               // 2304*18 int
    short* ws_xT     = (short*)(ws + 414720);               // 8*2304*128 bf16
    bf16x8_t* ws_bp  = (bf16x8_t*)(ws + 5133312);           // packed Wu bf16 (589824 B)

    params_kernel<<<HW, 64, 0, stream>>>(W1, b1, W2, b2, ws_means, ws_sigma, ws_fl);
    transpose_kernel<<<dim3(HW/64, CIN/64, BB), 256, 0, stream>>>(
        x, (__hip_bfloat16*)ws_xT);
    pack_wu<<<144, 256, 0, stream>>>(Wu, ws_bp);
    fused_kernel<<<MM/MT, 256, 0, stream>>>(ws_means, ws_sigma, ws_fl, gints, roff,
                                            ws_xT, ws_bp, bu, out);
}

// Round 4
// 146.122 us; speedup vs baseline: 1.3083x; 1.0587x over previous
//
#include <hip/hip_runtime.h>
#include <hip/hip_bf16.h>

// Problem constants
#define BB 8
#define CIN 128
#define HH 48
#define WW 48
#define HW 2304          // 48*48
#define KK 9
#define COUT 256
#define KC 1152          // K*CIN
#define MM 18432         // B*HW
#define MT 32            // M-tile rows per block (fused kernel)
#define SFP 136          // feats LDS row stride in elements (16B-aligned, 4-way bank)

typedef short bf16x8_t __attribute__((ext_vector_type(8)));
typedef float f32x16_t __attribute__((ext_vector_type(16)));
typedef float f32x4_t  __attribute__((ext_vector_type(4)));

static __device__ __forceinline__ float b2f(short u) {
    union { unsigned int i; float f; } c;
    c.i = ((unsigned int)(unsigned short)u) << 16;
    return c.f;
}

// ---------------------------------------------------------------------------
// PREP kernel: one launch does transpose (blocks 0..575), pack_wu (576..719),
// params MLP (720..1295; 4 positions per block, one wave each).
// ---------------------------------------------------------------------------
__global__ __launch_bounds__(256) void prep_kernel(
    const float* __restrict__ x, __hip_bfloat16* __restrict__ xT,
    const float* __restrict__ Wu, bf16x8_t* __restrict__ Bp,
    const float* __restrict__ W1, const float* __restrict__ b1,
    const float* __restrict__ W2, const float* __restrict__ b2,
    float* __restrict__ means, float* __restrict__ sigmas, int* __restrict__ fls)
{
    int bid = blockIdx.x;
    int t = threadIdx.x;

    if (bid < 576) {
        // ---- transpose x (b,c,h,w) fp32 -> xT (b,hw,c) bf16
        __shared__ float tile[64][65];
        int ij0 = (bid % 36) * 64;
        int c0  = ((bid / 36) % 2) * 64;
        int b   = bid / 72;
        int ijl = t & 63, cl = t >> 6;
        #pragma unroll
        for (int i = 0; i < 16; i++) {
            int cc = i*4 + cl;
            tile[cc][ijl] = x[(size_t)(b*CIN + c0 + cc) * HW + ij0 + ijl];
        }
        __syncthreads();
        int cl2 = t & 63, ijl2 = t >> 6;
        #pragma unroll
        for (int i = 0; i < 16; i++) {
            int ij = i*4 + ijl2;
            xT[(size_t)(b*HW + ij0 + ij) * CIN + c0 + cl2] = __float2bfloat16(tile[cl2][ij]);
        }
    } else if (bid < 720) {
        // ---- pack Wu fp32 -> bf16 fragments
        // Bp[(g*72+s)*64+lane]: Wu[g*32 + (lane&31)][s*16 + (lane>>5)*8 + j]
        int idx = (bid - 576) * 256 + t;          // 0 .. 36863
        int lane = idx & 63;
        int rest = idx >> 6;
        int s = rest % 72, g = rest / 72;
        int r = lane & 31, qq = lane >> 5;
        const float* src = Wu + (size_t)(g*32 + r) * KC + s*16 + qq*8;
        union { bf16x8_t v; __hip_bfloat16 h[8]; } o;
        #pragma unroll
        for (int j = 0; j < 8; j++) o.h[j] = __float2bfloat16(src[j]);
        Bp[idx] = o.v;
    } else {
        // ---- params MLP, wave-parallel fp64. One wave per position.
        int wave = t >> 6, lane = t & 63;
        int p = (bid - 720) * 4 + wave;           // 0..2303
        int iy = p / WW, ix = p % WW;
        float ryf = (float)iy / 47.0f;
        float rxf = (float)ix / 47.0f;
        double ry = (double)ryf, rx = (double)rxf;

        // hid[lane*8 .. lane*8+7] in registers
        double h[8];
        #pragma unroll
        for (int jj = 0; jj < 8; jj++) {
            int j = lane*8 + jj;
            double v = ry * (double)W1[j*2+0] + rx * (double)W1[j*2+1] + (double)b1[j];
            h[jj] = v > 0.0 ? v : 0.0;
        }
        // 27 partial dots, coalesced W2 reads (float4 x2 per output)
        double par[27];
        #pragma unroll
        for (int o = 0; o < 27; o++) {
            const float4* w4 = (const float4*)(W2 + (size_t)o*512 + lane*8);
            float4 wa = w4[0], wb = w4[1];
            double s = (double)wa.x*h[0] + (double)wa.y*h[1]
                     + (double)wa.z*h[2] + (double)wa.w*h[3]
                     + (double)wb.x*h[4] + (double)wb.y*h[5]
                     + (double)wb.z*h[6] + (double)wb.w*h[7];
            par[o] = s;
        }
        // butterfly reduce across 64 lanes (every lane ends with full sum)
        #pragma unroll
        for (int o = 0; o < 27; o++) {
            #pragma unroll
            for (int d = 1; d < 64; d <<= 1)
                par[o] += __shfl_xor(par[o], d, 64);
            par[o] += (double)b2[o];
        }
        if (lane < KK) {
            int k = lane;
            double scy = ry * 0.9999 + 5e-05;   // pix/(s-1) == ry
            double scx = rx * 0.9999 + 5e-05;
            double midy = log(scy / (1.0 - scy));
            double midx = log(scx / (1.0 - scx));
            double zy = midy + 0.1 * par[2*k+0];
            double zx = midx + 0.1 * par[2*k+1];
            double my = 47.0 / (1.0 + exp(-zy));
            double mx = 47.0 / (1.0 + exp(-zx));
            double sr = par[18 + k] + 2.0;
            double sp = (sr > 0.0 ? sr : 0.0) + log1p(exp(-fabs(sr)));
            double sg = (sp + 0.05) * 48.0 * 0.05;
            means[(p*KK + k)*2 + 0] = (float)my;
            means[(p*KK + k)*2 + 1] = (float)mx;
            sigmas[p*KK + k] = (float)sg;
            fls[(p*KK + k)*2 + 0] = (int)floor(my);
            fls[(p*KK + k)*2 + 1] = (int)floor(mx);
        }
    }
}

// ---------------------------------------------------------------------------
// FUSED gather + GEMM, software-pipelined.
// Block: 512 threads (8 waves). M-tile = 32 rows, wave w covers n = w*32..+31.
// Per chunk k: [issue tap loads k] [MFMA k-1] [issue Bf k] [math k -> LDS] [bar]
// ---------------------------------------------------------------------------
__global__ __launch_bounds__(512, 4) void fused_kernel(
    const float* __restrict__ means, const float* __restrict__ sigmas,
    const int* __restrict__ fls, const int* __restrict__ gints,
    const int* __restrict__ roff, const short* __restrict__ xT,
    const bf16x8_t* __restrict__ Bp, const float* __restrict__ bu,
    float* __restrict__ out)
{
    __shared__ int2 s_tap[KK*MT*8];                      // (lin, w bits) 18432 B
    __shared__ __align__(16) short s_feat[2][MT*SFP];    // 17408 B

    int t = threadIdx.x;
    int m0 = blockIdx.x * MT;
    int b  = m0 / HW;
    int ij0 = m0 % HW;

    // ---- setup: taps + dup-kill + normalized weights for all (row,k)
    if (t < KK*MT) {
        int p = t;
        int k = p >> 5, row = p & 31;
        int ij = ij0 + row;
        int bij = m0 + row;
        int fy = fls[(ij*KK + k)*2 + 0];
        int fx = fls[(ij*KK + k)*2 + 1];
        float my = means[(ij*KK + k)*2 + 0];
        float mx = means[(ij*KK + k)*2 + 1];
        float sg = sigmas[ij*KK + k];
        int lins[8]; float ws[8];
        #pragma unroll
        for (int v = 0; v < 8; v++) {
            int iy, ix;
            if (v < 4) {
                iy = fy + (v >> 1); ix = fx + (v & 1);
            } else if (v < 6) {
                int base = ((bij*KK + k)*2 + (v - 4)) * 2;
                iy = gints[base]; ix = gints[base + 1];
            } else {
                int base = ((bij*KK + k)*2 + (v - 6)) * 2;
                iy = fy + roff[base] - 6; ix = fx + roff[base + 1] - 6;
            }
            iy = ((iy % HH) + HH) % HH;
            ix = ((ix % WW) + WW) % WW;
            lins[v] = iy * WW + ix;
            float dy = ((float)iy - my) / sg;
            float dx = ((float)ix - mx) / sg;
            ws[v] = expf(-0.5f * (dy*dy + dx*dx));
        }
        #pragma unroll
        for (int v = 1; v < 8; v++) {
            bool dup = false;
            #pragma unroll
            for (int u = 0; u < 8; u++) if (u < v) dup = dup || (lins[u] == lins[v]);
            if (dup) ws[v] = 0.0f;
        }
        float sum = 0.0f;
        #pragma unroll
        for (int v = 0; v < 8; v++) sum += ws[v];
        float inv = 1.0f / sum;
        #pragma unroll
        for (int v = 0; v < 8; v++)
            s_tap[p*8+v] = make_int2(lins[v], __float_as_int(ws[v] * inv));
    }
    __syncthreads();

    const short* xb = xT + (size_t)b * (HW * CIN);
    int lane = t & 63, wave = t >> 6;
    int r = lane & 31, q = lane >> 5;
    int grow = t >> 4, gc0 = (t & 15) << 3;   // gather: row (0..31), 8-ch base

    f32x16_t acc = {};
    bf16x8_t Bf[8];
    bf16x8_t tap[8];
    float    wgt[8];

    #pragma unroll
    for (int k = 0; k < KK; k++) {
        // a) read tap descriptors for chunk k, issue gather loads
        {
            const int2* tp = &s_tap[(k*MT + grow)*8];
            #pragma unroll
            for (int v = 0; v < 8; v++) {
                int2 e = tp[v];
                wgt[v] = __int_as_float(e.y);
                tap[v] = *(const bf16x8_t*)(xb + (size_t)e.x * CIN + gc0);
            }
        }
        // b) MFMA on chunk k-1 (covers tap-load latency)
        if (k > 0) {
            const short* fb = s_feat[(k-1) & 1];
            #pragma unroll
            for (int si = 0; si < 8; si++) {
                bf16x8_t a = *(const bf16x8_t*)(fb + r*SFP + si*16 + q*8);
                acc = __builtin_amdgcn_mfma_f32_32x32x16_bf16(a, Bf[si], acc, 0, 0, 0);
            }
        }
        // c) issue B-fragment loads for chunk k (consumed next iter / epilogue)
        {
            int base = (wave*72 + k*8)*64 + lane;
            #pragma unroll
            for (int si = 0; si < 8; si++) Bf[si] = Bp[base + si*64];
        }
        // d) gather math chunk k -> LDS
        {
            float a0[8];
            #pragma unroll
            for (int j = 0; j < 8; j++) a0[j] = 0.0f;
            #pragma unroll
            for (int v = 0; v < 8; v++) {
                float w = wgt[v];
                bf16x8_t d8 = tap[v];
                #pragma unroll
                for (int j = 0; j < 8; j++) a0[j] += w * b2f(d8[j]);
            }
            union { bf16x8_t v8; __hip_bfloat16 hh[8]; } o;
            #pragma unroll
            for (int j = 0; j < 8; j++) o.hh[j] = __float2bfloat16(a0[j]);
            *(bf16x8_t*)(&s_feat[k & 1][grow*SFP + gc0]) = o.v8;
        }
        __syncthreads();
    }
    // final MFMA on chunk 8
    {
        const short* fb = s_feat[(KK-1) & 1];
        #pragma unroll
        for (int si = 0; si < 8; si++) {
            bf16x8_t a = *(const bf16x8_t*)(fb + r*SFP + si*16 + q*8);
            acc = __builtin_amdgcn_mfma_f32_32x32x16_bf16(a, Bf[si], acc, 0, 0, 0);
        }
    }

    // ---- epilogue: C col = r (n), row = (reg&3)+8*(reg>>2)+4*q
    int n = wave*32 + r;
    float bv = bu[n];
    float* oc = out + ((size_t)b * COUT + n) * HW + ij0;
    #pragma unroll
    for (int g4 = 0; g4 < 4; g4++) {
        f32x4_t vv;
        vv[0] = acc[g4*4+0] + bv;
        vv[1] = acc[g4*4+1] + bv;
        vv[2] = acc[g4*4+2] + bv;
        vv[3] = acc[g4*4+3] + bv;
        *(f32x4_t*)(oc + g4*8 + q*4) = vv;
    }
}

// ---------------------------------------------------------------------------
extern "C" void kernel_launch(void* const* d_in, const int* in_sizes, int n_in,
                              void* d_out, int out_size, void* d_ws, size_t ws_size,
                              hipStream_t stream)
{
    const float* x   = (const float*)d_in[0];
    const float* W1  = (const float*)d_in[1];
    const float* b1  = (const float*)d_in[2];
    const float* W2  = (const float*)d_in[3];
    const float* b2  = (const float*)d_in[4];
    const float* Wu  = (const float*)d_in[5];
    const float* bu  = (const float*)d_in[6];
    const int* gints = (const int*)d_in[7];
    const int* roff  = (const int*)d_in[8];
    float* out = (float*)d_out;

    char* ws = (char*)d_ws;
    float* ws_means  = (float*)(ws + 0);                    // 2304*18 fp32
    float* ws_sigma  = (float*)(ws + 165888);               // 2304*9  fp32
    int*   ws_fl     = (int*  )(ws + 248832);               // 2304*18 int
    short* ws_xT     = (short*)(ws + 414720);               // 8*2304*128 bf16
    bf16x8_t* ws_bp  = (bf16x8_t*)(ws + 5133312);           // packed Wu bf16

    prep_kernel<<<1296, 256, 0, stream>>>(x, (__hip_bfloat16*)ws_xT, Wu, ws_bp,
                                          W1, b1, W2, b2,
                                          ws_means, ws_sigma, ws_fl);
    fused_kernel<<<MM/MT, 512, 0, stream>>>(ws_means, ws_sigma, ws_fl, gints, roff,
                                            ws_xT, ws_bp, bu, out);
}